// Round 14
// baseline (588.974 us; speedup 1.0000x reference)
//
#include <hip/hip_runtime.h>
#include <hip/hip_cooperative_groups.h>
#include <hip/hip_fp16.h>
#include <math.h>

#define B_   16
#define I_   2048
#define AIN_ 16
#define O_   64
#define J_   2048     // O*A_OUT
#define JP_  1024     // j as half2 / float2 pair-columns

namespace cg = cooperative_groups;

// non-temporal float2 load (W is a read-once 268 MB stream; keep it out of
// L3 so the 64 MB f16 votes working set stays resident for the route passes)
__device__ __forceinline__ float2 ntload2(const float2* p) {
  union { double d; float2 f; } u;
  u.d = __builtin_nontemporal_load((const double*)p);
  return u.f;
}

// unpack a uint4 of 4 half2 (8 j) to 4 float2
__device__ __forceinline__ void unp8(const uint4 u, float2* f) {
  const __half2* h = (const __half2*)&u;
  f[0] = __half22float2(h[0]); f[1] = __half22float2(h[1]);
  f[2] = __half22float2(h[2]); f[3] = __half22float2(h[3]);
}
// pack 8 f32 (two float4) into a uint4 of half2
__device__ __forceinline__ uint4 pk8(float4 a, float4 b) {
  union { uint4 u; __half2 h[4]; } r;
  r.h[0] = __float22half2_rn(make_float2(a.x, a.y));
  r.h[1] = __float22half2_rn(make_float2(a.z, a.w));
  r.h[2] = __float22half2_rn(make_float2(b.x, b.y));
  r.h[3] = __float22half2_rn(make_float2(b.z, b.w));
  return r.u;
}

// -------------------------------------------------------------------------
// votes_p0_kernel — unchanged from round 12 (HBM-bound at its floor).
// -------------------------------------------------------------------------
__global__ __launch_bounds__(256) void votes_p0_kernel(
    const float* __restrict__ x, const float* __restrict__ W,
    __half2* __restrict__ votes, __half2* __restrict__ part0)
{
  __shared__ __half2 x_lds[4][B_][AIN_];   // broadcast pairs (x_a,x_a); 4 KB
  const int tid = threadIdx.x;
  const int islab = blockIdx.x >> 2, jt = blockIdx.x & 3;
  const int i0 = islab * 4;

  for (int e = tid; e < 4 * B_ * AIN_; e += 256) {
    int il = e >> 8, b = (e >> 4) & 15, a = e & 15;
    float xv = x[((size_t)b * I_ + (i0 + il)) * AIN_ + a];
    x_lds[il][b][a] = __float2half2_rn(xv);
  }
  __syncthreads();

  const int jp = jt * 256 + tid;               // half2 column 0..1023
  __half2 acc[16];
  #pragma unroll
  for (int b = 0; b < 16; ++b) acc[b] = __float2half2_rn(0.f);

  for (int il = 0; il < 4; ++il) {
    const int i = i0 + il;
    const float2* __restrict__ Wi =
        (const float2*)W + (size_t)i * (AIN_ * JP_) + jp;

    __half2 v[16];
    #pragma unroll
    for (int b = 0; b < 16; ++b) v[b] = __float2half2_rn(0.f);

    #pragma unroll
    for (int a2 = 0; a2 < 8; ++a2) {
      __half2 w0 = __float22half2_rn(ntload2(Wi + (size_t)(2 * a2 + 0) * JP_));
      __half2 w1 = __float22half2_rn(ntload2(Wi + (size_t)(2 * a2 + 1) * JP_));
      #pragma unroll
      for (int b = 0; b < 16; ++b) {
        v[b] = __hfma2(x_lds[il][b][2 * a2],     w0, v[b]);
        v[b] = __hfma2(x_lds[il][b][2 * a2 + 1], w1, v[b]);
      }
    }

    __half2* __restrict__ vo = votes + (size_t)i * (B_ * JP_) + jp;
    #pragma unroll
    for (int b = 0; b < 16; ++b) {
      vo[(size_t)b * JP_] = v[b];
      acc[b] = __hadd2(acc[b], v[b]);
    }
  }

  const __half2 s64 = __float2half2_rn(1.0f / 64.0f);
  __half2* __restrict__ po = part0 + (size_t)blockIdx.x * (B_ * 256) + tid;
  #pragma unroll
  for (int b = 0; b < 16; ++b)
    po[(size_t)b * 256] = __hmul2(acc[b], s64);
}

// -------------------------------------------------------------------------
// Inline phase bodies (shared by standalone kernels and the mega kernel).
// smem: 2048 floats (8 KB), used as red[64][4][8] by reducers and
// d_lds[128]/r_lds[128] by route.
// -------------------------------------------------------------------------
__device__ __forceinline__ void reduce0_body(
    int bid, const uint4* __restrict__ part0, const float* __restrict__ bias,
    float* __restrict__ act, float* smem)
{
  const int b = bid >> 6, o = bid & 63;
  const int t = threadIdx.x, s = t >> 2, q = t & 3;
  const uint4* __restrict__ base =
      part0 + (size_t)(o >> 4) * 1024 + b * 64 + (o & 15) * 4 + q;

  float r[8];
  #pragma unroll
  for (int e = 0; e < 8; ++e) r[e] = 0.f;
  #pragma unroll
  for (int k = 0; k < 8; ++k) {
    uint4 u = base[(size_t)(s + 64 * k) * 4096];
    float2 f[4];
    unp8(u, f);
    r[0] += f[0].x; r[1] += f[0].y; r[2] += f[1].x; r[3] += f[1].y;
    r[4] += f[2].x; r[5] += f[2].y; r[6] += f[3].x; r[7] += f[3].y;
  }
  #pragma unroll
  for (int e = 0; e < 8; ++e) smem[(s * 4 + q) * 8 + e] = r[e];
  __syncthreads();

  if (t < 32) {
    const int q2 = t >> 3, e = t & 7;
    float p = 0.f;
    for (int s2 = 0; s2 < 64; ++s2) p += smem[(s2 * 4 + q2) * 8 + e];
    p += bias[o * 32 + q2 * 8 + e];
    float ns = p * p;
    ns += __shfl_xor(ns, 1);  ns += __shfl_xor(ns, 2);
    ns += __shfl_xor(ns, 4);  ns += __shfl_xor(ns, 8);
    ns += __shfl_xor(ns, 16);
    act[(size_t)b * J_ + o * 32 + q2 * 8 + e] = p * sqrtf(ns) / (1.0f + ns);
  }
}

__device__ __forceinline__ void reduce_body(
    int bid, const uint4* __restrict__ part, const float* __restrict__ bias,
    float* __restrict__ dst, float* smem)
{
  const int b = bid >> 6, o = bid & 63;
  const int t = threadIdx.x, s = t >> 2, q = t & 3;
  const uint4* __restrict__ base = part + (size_t)b * 256 + o * 4 + q;

  float r[8];
  #pragma unroll
  for (int e = 0; e < 8; ++e) r[e] = 0.f;
  #pragma unroll
  for (int k = 0; k < 4; ++k) {
    uint4 u = base[(size_t)(s + 64 * k) * 4096];
    float2 f[4];
    unp8(u, f);
    r[0] += f[0].x; r[1] += f[0].y; r[2] += f[1].x; r[3] += f[1].y;
    r[4] += f[2].x; r[5] += f[2].y; r[6] += f[3].x; r[7] += f[3].y;
  }
  #pragma unroll
  for (int e = 0; e < 8; ++e) smem[(s * 4 + q) * 8 + e] = r[e];
  __syncthreads();

  if (t < 32) {
    const int q2 = t >> 3, e = t & 7;
    float p = 0.f;
    for (int s2 = 0; s2 < 64; ++s2) p += smem[(s2 * 4 + q2) * 8 + e];
    p += bias[o * 32 + q2 * 8 + e];
    float ns = p * p;
    ns += __shfl_xor(ns, 1);  ns += __shfl_xor(ns, 2);
    ns += __shfl_xor(ns, 4);  ns += __shfl_xor(ns, 8);
    ns += __shfl_xor(ns, 16);
    dst[(size_t)b * J_ + o * 32 + q2 * 8 + e] = p * sqrtf(ns) / (1.0f + ns);
  }
}

// route body == round-12 route_kernel (proven 16-barrier structure),
// parameterized on sub-block id sb in [0,2048).
template<int PASS>
__device__ __forceinline__ void route_body(
    int sb, const uint4* __restrict__ votes4, const float* __restrict__ act_in,
    uint4* __restrict__ part, float* __restrict__ logits, float* smem)
{
  float* d_lds = smem;           // [128]
  float* r_lds = smem + 128;     // [128]
  const int t = threadIdx.x;
  const int islab = sb >> 3, bq = sb & 7;
  const int i0 = islab * 8;
  const int o = t >> 2, l4 = t & 3;            // 4 threads per o, 8 j each
  const float4* __restrict__ actq = (const float4*)act_in;

  float4 av00 = actq[(size_t)(bq * 2 + 0) * 512 + 2 * t];
  float4 av01 = actq[(size_t)(bq * 2 + 0) * 512 + 2 * t + 1];
  float4 av10 = actq[(size_t)(bq * 2 + 1) * 512 + 2 * t];
  float4 av11 = actq[(size_t)(bq * 2 + 1) * 512 + 2 * t + 1];

  float4 ac00 = make_float4(0,0,0,0), ac01 = make_float4(0,0,0,0);
  float4 ac10 = make_float4(0,0,0,0), ac11 = make_float4(0,0,0,0);

  for (int il = 0; il < 8; ++il) {
    const int i = i0 + il;
    float lgv = 0.f;
    if (PASS == 2 && t < 128)                   // prefetch: hides under dist
      lgv = logits[((size_t)(bq * 2 + (t >> 6)) * I_ + i) * O_ + (t & 63)];

    const uint4* __restrict__ vo =
        votes4 + (size_t)i * 4096 + (size_t)(bq * 2) * 256 + t;
    float2 f0[4], f1[4];
    unp8(vo[0],   f0);
    unp8(vo[256], f1);

    float c0 = f0[0].x*av00.x + f0[0].y*av00.y + f0[1].x*av00.z + f0[1].y*av00.w
             + f0[2].x*av01.x + f0[2].y*av01.y + f0[3].x*av01.z + f0[3].y*av01.w;
    c0 += __shfl_xor(c0, 1);  c0 += __shfl_xor(c0, 2);
    float c1 = f1[0].x*av10.x + f1[0].y*av10.y + f1[1].x*av10.z + f1[1].y*av10.w
             + f1[2].x*av11.x + f1[2].y*av11.y + f1[3].x*av11.z + f1[3].y*av11.w;
    c1 += __shfl_xor(c1, 1);  c1 += __shfl_xor(c1, 2);
    if (l4 == 0) d_lds[o]      = c0;
    if (l4 == 1) d_lds[64 + o] = c1;
    __syncthreads();

    float ellsave = 0.f;
    if (t < 128) {
      float ell = d_lds[t];
      if (PASS == 2) ell += lgv;
      ellsave = ell;
      float m = ell;
      m = fmaxf(m, __shfl_xor(m, 32)); m = fmaxf(m, __shfl_xor(m, 16));
      m = fmaxf(m, __shfl_xor(m, 8));  m = fmaxf(m, __shfl_xor(m, 4));
      m = fmaxf(m, __shfl_xor(m, 2));  m = fmaxf(m, __shfl_xor(m, 1));
      float e = __expf(ell - m);
      float sd = e;
      sd += __shfl_xor(sd, 32); sd += __shfl_xor(sd, 16); sd += __shfl_xor(sd, 8);
      sd += __shfl_xor(sd, 4);  sd += __shfl_xor(sd, 2);  sd += __shfl_xor(sd, 1);
      r_lds[t] = e / sd;
    }
    __syncthreads();

    if (PASS == 1 && t < 128)                   // deferred: drains next il
      logits[((size_t)(bq * 2 + (t >> 6)) * I_ + i) * O_ + (t & 63)] = ellsave;

    float r0 = r_lds[o], r1 = r_lds[64 + o];
    ac00.x = fmaf(r0, f0[0].x, ac00.x); ac00.y = fmaf(r0, f0[0].y, ac00.y);
    ac00.z = fmaf(r0, f0[1].x, ac00.z); ac00.w = fmaf(r0, f0[1].y, ac00.w);
    ac01.x = fmaf(r0, f0[2].x, ac01.x); ac01.y = fmaf(r0, f0[2].y, ac01.y);
    ac01.z = fmaf(r0, f0[3].x, ac01.z); ac01.w = fmaf(r0, f0[3].y, ac01.w);
    ac10.x = fmaf(r1, f1[0].x, ac10.x); ac10.y = fmaf(r1, f1[0].y, ac10.y);
    ac10.z = fmaf(r1, f1[1].x, ac10.z); ac10.w = fmaf(r1, f1[1].y, ac10.w);
    ac11.x = fmaf(r1, f1[2].x, ac11.x); ac11.y = fmaf(r1, f1[2].y, ac11.y);
    ac11.z = fmaf(r1, f1[3].x, ac11.z); ac11.w = fmaf(r1, f1[3].y, ac11.w);
  }

  uint4* __restrict__ po =
      part + (size_t)islab * 4096 + (size_t)(bq * 2) * 256 + t;
  po[0]   = pk8(ac00, ac01);
  po[256] = pk8(ac10, ac11);
}

// -------------------------------------------------------------------------
// routing_mega: stages 2-6 fused via grid.sync(). Grid 1024 x 256;
// __launch_bounds__(256,4) caps VGPR at 128 -> >=16 waves/CU residency ->
// all 1024 blocks (4/CU) co-resident by construction (2x safety margin).
// Route phases run 2 sub-blocks each to cover the 2048-sub-block geometry.
// -------------------------------------------------------------------------
__global__ __launch_bounds__(256, 4) void routing_mega(
    const uint4* __restrict__ votes4, uint4* __restrict__ part,
    const float* __restrict__ bias, float* __restrict__ act,
    float* __restrict__ logits, float* __restrict__ out)
{
  __shared__ float smem[2048];                 // 8 KB, reused across phases
  cg::grid_group grid = cg::this_grid();

  reduce0_body(blockIdx.x, part, bias, act, smem);   // part == part0 here
  grid.sync();
  route_body<1>(blockIdx.x * 2 + 0, votes4, act, part, logits, smem);
  __syncthreads();
  route_body<1>(blockIdx.x * 2 + 1, votes4, act, part, logits, smem);
  grid.sync();
  reduce_body(blockIdx.x, part, bias, act, smem);
  grid.sync();
  route_body<2>(blockIdx.x * 2 + 0, votes4, act, part, logits, smem);
  __syncthreads();
  route_body<2>(blockIdx.x * 2 + 1, votes4, act, part, logits, smem);
  grid.sync();
  reduce_body(blockIdx.x, part, bias, out, smem);
}

// -------------------------------------------------------------------------
// Standalone wrappers (fallback when cooperative launch is unavailable) —
// identical math to round 12 via the shared bodies.
// -------------------------------------------------------------------------
__global__ __launch_bounds__(256) void reduce_squash0_f16(
    const uint4* __restrict__ part0, const float* __restrict__ bias,
    float* __restrict__ act)
{
  __shared__ float smem[2048];
  reduce0_body(blockIdx.x, part0, bias, act, smem);
}

template<int PASS>
__global__ __launch_bounds__(256) void route_kernel(
    const uint4* __restrict__ votes4, const float* __restrict__ act_in,
    uint4* __restrict__ part, float* __restrict__ logits)
{
  __shared__ float smem[256];
  route_body<PASS>(blockIdx.x, votes4, act_in, part, logits, smem);
}

__global__ __launch_bounds__(256) void reduce_squash_f16(
    const uint4* __restrict__ part, const float* __restrict__ bias,
    float* __restrict__ out)
{
  __shared__ float smem[2048];
  reduce_body(blockIdx.x, part, bias, out, smem);
}

// -------------------------------------------------------------------------
// FALLBACK (ws too small): W-streaming f32 path (unchanged).
// -------------------------------------------------------------------------
__global__ __launch_bounds__(256) void reduce_squash_f32(
    const float* __restrict__ part, const float* __restrict__ bias,
    float* __restrict__ out)
{
  __shared__ float4 red[32][8];
  const int b = blockIdx.x >> 6, o = blockIdx.x & 63;
  const int t = threadIdx.x, s = t >> 3, q = t & 7;
  const float4* __restrict__ base =
      (const float4*)part + (size_t)b * 512 + o * 8 + q;

  float4 acc = make_float4(0.f, 0.f, 0.f, 0.f);
  #pragma unroll
  for (int k = 0; k < 8; ++k) {
    float4 v = base[(size_t)(s + 32 * k) * 8192];
    acc.x += v.x; acc.y += v.y; acc.z += v.z; acc.w += v.w;
  }
  red[s][q] = acc;
  __syncthreads();

  if (t < 8) {
    float4 p = make_float4(0.f, 0.f, 0.f, 0.f);
    for (int s2 = 0; s2 < 32; ++s2) {
      float4 v = red[s2][t];
      p.x += v.x; p.y += v.y; p.z += v.z; p.w += v.w;
    }
    float4 bq4 = ((const float4*)bias)[o * 8 + t];
    p.x += bq4.x; p.y += bq4.y; p.z += bq4.z; p.w += bq4.w;
    float ns = p.x*p.x + p.y*p.y + p.z*p.z + p.w*p.w;
    ns += __shfl_xor(ns, 1);  ns += __shfl_xor(ns, 2);  ns += __shfl_xor(ns, 4);
    float sc = sqrtf(ns) / (1.0f + ns);
    ((float4*)out)[(size_t)b * 512 + o * 8 + t] =
        make_float4(p.x*sc, p.y*sc, p.z*sc, p.w*sc);
  }
}

template<int PASS>
__global__ __launch_bounds__(1024) void fb_pass_kernel(
    const float* __restrict__ x, const float* __restrict__ W,
    const float* __restrict__ act_in, float* __restrict__ part,
    float* __restrict__ logits)
{
  __shared__ float x_lds[8 * B_ * AIN_];
  __shared__ float d_lds[8 * O_];
  __shared__ float r_lds[8 * O_];
  const int tid = threadIdx.x, blk = blockIdx.x, i0 = blk * 8;
  for (int e = tid; e < 8 * B_ * AIN_; e += 1024) {
    int b = e >> 7, il = (e >> 4) & 7, a = e & 15;
    x_lds[il * 256 + b * 16 + a] =
        x[(size_t)b * (I_ * AIN_) + (size_t)(i0 + il) * AIN_ + a];
  }
  __syncthreads();
  const int og = tid >> 4, lg = tid & 15;
  float2 acc[16];
  #pragma unroll
  for (int b = 0; b < 16; ++b) acc[b] = make_float2(0.f, 0.f);
  const float2* __restrict__ Wq   = (const float2*)W;
  const float2* __restrict__ actq = (const float2*)act_in;
  for (int il = 0; il < 8; ++il) {
    const int i = i0 + il;
    const float2* __restrict__ Wi = Wq + (size_t)i * (AIN_ * JP_);
    const float4* __restrict__ xq = (const float4*)x_lds + il * 64;
    for (int h = 0; h < 2; ++h) {
      float2 v[8];
      #pragma unroll
      for (int bb = 0; bb < 8; ++bb) v[bb] = make_float2(0.f, 0.f);
      #pragma unroll
      for (int a4 = 0; a4 < 4; ++a4) {
        float2 w0 = Wi[(size_t)(a4 * 4 + 0) * JP_ + tid];
        float2 w1 = Wi[(size_t)(a4 * 4 + 1) * JP_ + tid];
        float2 w2 = Wi[(size_t)(a4 * 4 + 2) * JP_ + tid];
        float2 w3 = Wi[(size_t)(a4 * 4 + 3) * JP_ + tid];
        #pragma unroll
        for (int bb = 0; bb < 8; ++bb) {
          float4 xv = xq[(h * 8 + bb) * 4 + a4];
          v[bb].x = fmaf(xv.x, w0.x, v[bb].x); v[bb].y = fmaf(xv.x, w0.y, v[bb].y);
          v[bb].x = fmaf(xv.y, w1.x, v[bb].x); v[bb].y = fmaf(xv.y, w1.y, v[bb].y);
          v[bb].x = fmaf(xv.z, w2.x, v[bb].x); v[bb].y = fmaf(xv.z, w2.y, v[bb].y);
          v[bb].x = fmaf(xv.w, w3.x, v[bb].x); v[bb].y = fmaf(xv.w, w3.y, v[bb].y);
        }
      }
      if (PASS == 0) {
        #pragma unroll
        for (int bb = 0; bb < 8; ++bb) {
          acc[h * 8 + bb].x += v[bb].x; acc[h * 8 + bb].y += v[bb].y;
        }
      } else {
        #pragma unroll
        for (int bb = 0; bb < 8; ++bb) {
          const int b = h * 8 + bb;
          float2 avv = actq[(size_t)b * JP_ + tid];
          float c = v[bb].x * avv.x + v[bb].y * avv.y;
          c += __shfl_xor(c, 1); c += __shfl_xor(c, 2);
          c += __shfl_xor(c, 4); c += __shfl_xor(c, 8);
          if (lg == bb) d_lds[bb * 64 + og] = c;
        }
        __syncthreads();
        if (tid < 512) {
          const int bb2 = tid >> 6, o2 = tid & 63;
          const int b2  = h * 8 + bb2;
          float ell = d_lds[tid];
          if (PASS == 2) ell += logits[((size_t)b2 * I_ + i) * O_ + o2];
          if (PASS == 1) logits[((size_t)b2 * I_ + i) * O_ + o2] = ell;
          float m = ell;
          m = fmaxf(m, __shfl_xor(m, 32)); m = fmaxf(m, __shfl_xor(m, 16));
          m = fmaxf(m, __shfl_xor(m, 8));  m = fmaxf(m, __shfl_xor(m, 4));
          m = fmaxf(m, __shfl_xor(m, 2));  m = fmaxf(m, __shfl_xor(m, 1));
          float e = __expf(ell - m);
          float s = e;
          s += __shfl_xor(s, 32); s += __shfl_xor(s, 16); s += __shfl_xor(s, 8);
          s += __shfl_xor(s, 4);  s += __shfl_xor(s, 2);  s += __shfl_xor(s, 1);
          r_lds[tid] = e / s;
        }
        __syncthreads();
        #pragma unroll
        for (int bb = 0; bb < 8; ++bb) {
          float r = r_lds[bb * 64 + og];
          acc[h * 8 + bb].x = fmaf(r, v[bb].x, acc[h * 8 + bb].x);
          acc[h * 8 + bb].y = fmaf(r, v[bb].y, acc[h * 8 + bb].y);
        }
      }
    }
  }
  const float sc = (PASS == 0) ? (1.0f / 64.0f) : 1.0f;
  #pragma unroll
  for (int b = 0; b < 16; ++b) {
    float2* __restrict__ po = (float2*)part +
        (size_t)blk * (B_ * JP_) + (size_t)b * JP_ + tid;
    *po = make_float2(acc[b].x * sc, acc[b].y * sc);
  }
}

// -------------------------------------------------------------------------
extern "C" void kernel_launch(void* const* d_in, const int* in_sizes, int n_in,
                              void* d_out, int out_size, void* d_ws, size_t ws_size,
                              hipStream_t stream) {
  const float* x    = (const float*)d_in[0];
  const float* W    = (const float*)d_in[1];
  const float* bias = (const float*)d_in[2];
  float* out = (float*)d_out;

  float*   part   = (float*)d_ws;                        // 32 MiB region
  float*   act    = part + (size_t)256 * (B_ * J_);      // 128 KB
  float*   logits = act + (B_ * J_);                     // 8 MB
  __half2* votes  = (__half2*)(logits + (size_t)B_ * I_ * O_);  // 64 MB f16
  const size_t need = ((size_t)256 * B_ * J_ + B_ * J_ + (size_t)B_ * I_ * O_) * 4
                    + (size_t)I_ * B_ * JP_ * 4;

  if (ws_size >= need) {
    votes_p0_kernel<<<2048, 256, 0, stream>>>(x, W, votes, (__half2*)part);

    int coop = 0;
    int dev = 0;
    (void)hipGetDevice(&dev);
    (void)hipDeviceGetAttribute(&coop, hipDeviceAttributeCooperativeLaunch, dev);

    if (coop) {
      const uint4* votes4p = (const uint4*)votes;
      uint4*       partp   = (uint4*)part;
      const float* biasp   = bias;
      float*       actp    = act;
      float*       logitsp = logits;
      float*       outp    = out;
      void* args[] = { (void*)&votes4p, (void*)&partp, (void*)&biasp,
                       (void*)&actp, (void*)&logitsp, (void*)&outp };
      hipError_t e = hipLaunchCooperativeKernel(
          reinterpret_cast<void*>(&routing_mega),
          dim3(1024), dim3(256), args, 0, stream);
      if (e == hipSuccess) return;
      (void)hipGetLastError();   // clear; fall through to separate launches
    }

    reduce_squash0_f16<<<1024, 256, 0, stream>>>((const uint4*)part, bias, act);
    route_kernel<1><<<2048, 256, 0, stream>>>((const uint4*)votes, act,
                                              (uint4*)part, logits);
    reduce_squash_f16<<<1024, 256, 0, stream>>>((const uint4*)part, bias, act);
    route_kernel<2><<<2048, 256, 0, stream>>>((const uint4*)votes, act,
                                              (uint4*)part, logits);
    reduce_squash_f16<<<1024, 256, 0, stream>>>((const uint4*)part, bias, out);
  } else {
    fb_pass_kernel<0><<<256, 1024, 0, stream>>>(x, W, act, part, logits);
    reduce_squash_f32<<<1024, 256, 0, stream>>>(part, bias, act);
    fb_pass_kernel<1><<<256, 1024, 0, stream>>>(x, W, act, part, logits);
    reduce_squash_f32<<<1024, 256, 0, stream>>>(part, bias, act);
    fb_pass_kernel<2><<<256, 1024, 0, stream>>>(x, W, act, part, logits);
    reduce_squash_f32<<<1024, 256, 0, stream>>>(part, bias, out);
  }
}

// Round 15
// 164.608 us; speedup vs baseline: 3.5781x; 3.5781x over previous
//
#include <hip/hip_runtime.h>
#include <hip/hip_fp16.h>
#include <math.h>

#define B_   16
#define I_   2048
#define AIN_ 16
#define O_   64
#define J_   2048     // O*A_OUT
#define JP_  1024     // j as half2 / float2 pair-columns

// non-temporal float2 load (W is a read-once 268 MB stream; keep it out of
// L3 so the 64 MB f16 votes working set stays resident for the route passes)
__device__ __forceinline__ float2 ntload2(const float2* p) {
  union { double d; float2 f; } u;
  u.d = __builtin_nontemporal_load((const double*)p);
  return u.f;
}

// unpack a uint4 of 4 half2 (8 j) to 4 float2
__device__ __forceinline__ void unp8(const uint4 u, float2* f) {
  const __half2* h = (const __half2*)&u;
  f[0] = __half22float2(h[0]); f[1] = __half22float2(h[1]);
  f[2] = __half22float2(h[2]); f[3] = __half22float2(h[3]);
}
// pack 8 f32 (two float4) into a uint4 of half2
__device__ __forceinline__ uint4 pk8(float4 a, float4 b) {
  union { uint4 u; __half2 h[4]; } r;
  r.h[0] = __float22half2_rn(make_float2(a.x, a.y));
  r.h[1] = __float22half2_rn(make_float2(a.z, a.w));
  r.h[2] = __float22half2_rn(make_float2(b.x, b.y));
  r.h[3] = __float22half2_rn(make_float2(b.z, b.w));
  return r.u;
}

// -------------------------------------------------------------------------
// votes_p0_kernel — round-12 version (HBM-bound at its floor).
// votes[i,b,jp] (half2) + pass-0 partials -> part0 (half2); packed f16
// math; grid 2048 = 512 i-slabs(4 i) x 4 j-tiles; W read once (nt).
// -------------------------------------------------------------------------
__global__ __launch_bounds__(256) void votes_p0_kernel(
    const float* __restrict__ x, const float* __restrict__ W,
    __half2* __restrict__ votes, __half2* __restrict__ part0)
{
  __shared__ __half2 x_lds[4][B_][AIN_];   // broadcast pairs (x_a,x_a); 4 KB
  const int tid = threadIdx.x;
  const int islab = blockIdx.x >> 2, jt = blockIdx.x & 3;
  const int i0 = islab * 4;

  for (int e = tid; e < 4 * B_ * AIN_; e += 256) {
    int il = e >> 8, b = (e >> 4) & 15, a = e & 15;
    float xv = x[((size_t)b * I_ + (i0 + il)) * AIN_ + a];
    x_lds[il][b][a] = __float2half2_rn(xv);
  }
  __syncthreads();

  const int jp = jt * 256 + tid;               // half2 column 0..1023
  __half2 acc[16];
  #pragma unroll
  for (int b = 0; b < 16; ++b) acc[b] = __float2half2_rn(0.f);

  for (int il = 0; il < 4; ++il) {
    const int i = i0 + il;
    const float2* __restrict__ Wi =
        (const float2*)W + (size_t)i * (AIN_ * JP_) + jp;

    __half2 v[16];
    #pragma unroll
    for (int b = 0; b < 16; ++b) v[b] = __float2half2_rn(0.f);

    #pragma unroll
    for (int a2 = 0; a2 < 8; ++a2) {
      __half2 w0 = __float22half2_rn(ntload2(Wi + (size_t)(2 * a2 + 0) * JP_));
      __half2 w1 = __float22half2_rn(ntload2(Wi + (size_t)(2 * a2 + 1) * JP_));
      #pragma unroll
      for (int b = 0; b < 16; ++b) {
        v[b] = __hfma2(x_lds[il][b][2 * a2],     w0, v[b]);
        v[b] = __hfma2(x_lds[il][b][2 * a2 + 1], w1, v[b]);
      }
    }

    __half2* __restrict__ vo = votes + (size_t)i * (B_ * JP_) + jp;
    #pragma unroll
    for (int b = 0; b < 16; ++b) {
      vo[(size_t)b * JP_] = v[b];
      acc[b] = __hadd2(acc[b], v[b]);
    }
  }

  const __half2 s64 = __float2half2_rn(1.0f / 64.0f);
  // part0 layout: [slab = islab*4 + jt][16 b][256 half2]
  __half2* __restrict__ po = part0 + (size_t)blockIdx.x * (B_ * 256) + tid;
  #pragma unroll
  for (int b = 0; b < 16; ++b)
    po[(size_t)b * 256] = __hmul2(acc[b], s64);
}

// -------------------------------------------------------------------------
// reduce_squash0_f16 — round-12 version.
// -------------------------------------------------------------------------
__global__ __launch_bounds__(256) void reduce_squash0_f16(
    const uint4* __restrict__ part0, const float* __restrict__ bias,
    float* __restrict__ act)
{
  __shared__ float red[64][4][8];              // 8 KB
  const int b = blockIdx.x >> 6, o = blockIdx.x & 63;
  const int t = threadIdx.x, s = t >> 2, q = t & 3;
  const uint4* __restrict__ base =
      part0 + (size_t)(o >> 4) * 1024 + b * 64 + (o & 15) * 4 + q;

  float r[8];
  #pragma unroll
  for (int e = 0; e < 8; ++e) r[e] = 0.f;
  #pragma unroll
  for (int k = 0; k < 8; ++k) {
    uint4 u = base[(size_t)(s + 64 * k) * 4096];   // islab stride = 4 slabs
    float2 f[4];
    unp8(u, f);
    r[0] += f[0].x; r[1] += f[0].y; r[2] += f[1].x; r[3] += f[1].y;
    r[4] += f[2].x; r[5] += f[2].y; r[6] += f[3].x; r[7] += f[3].y;
  }
  #pragma unroll
  for (int e = 0; e < 8; ++e) red[s][q][e] = r[e];
  __syncthreads();

  if (t < 32) {
    const int q2 = t >> 3, e = t & 7;
    float p = 0.f;
    for (int s2 = 0; s2 < 64; ++s2) p += red[s2][q2][e];
    p += bias[o * 32 + q2 * 8 + e];
    float ns = p * p;                          // squash over 32-lane a-group
    ns += __shfl_xor(ns, 1);  ns += __shfl_xor(ns, 2);
    ns += __shfl_xor(ns, 4);  ns += __shfl_xor(ns, 8);
    ns += __shfl_xor(ns, 16);
    act[(size_t)b * J_ + o * 32 + q2 * 8 + e] = p * sqrtf(ns) / (1.0f + ns);
  }
}

// -------------------------------------------------------------------------
// route_kernel<PASS> (PASS = 1,2): round-12 version (proven best: 256-thr,
// 2 b x 8 i x all j, grid 2048 -> 8 blocks/CU, 16-barrier loop).
// -------------------------------------------------------------------------
template<int PASS>
__global__ __launch_bounds__(256) void route_kernel(
    const uint4* __restrict__ votes4, const float* __restrict__ act_in,
    uint4* __restrict__ part, float* __restrict__ logits)
{
  __shared__ float d_lds[128];                 // [bb][o]
  __shared__ float r_lds[128];

  const int t = threadIdx.x;
  const int islab = blockIdx.x >> 3, bq = blockIdx.x & 7;
  const int i0 = islab * 8;
  const int o = t >> 2, l4 = t & 3;            // 4 threads per o, 8 j each
  const float4* __restrict__ actq = (const float4*)act_in;

  float4 av00 = actq[(size_t)(bq * 2 + 0) * 512 + 2 * t];
  float4 av01 = actq[(size_t)(bq * 2 + 0) * 512 + 2 * t + 1];
  float4 av10 = actq[(size_t)(bq * 2 + 1) * 512 + 2 * t];
  float4 av11 = actq[(size_t)(bq * 2 + 1) * 512 + 2 * t + 1];

  float4 ac00 = make_float4(0,0,0,0), ac01 = make_float4(0,0,0,0);
  float4 ac10 = make_float4(0,0,0,0), ac11 = make_float4(0,0,0,0);

  for (int il = 0; il < 8; ++il) {
    const int i = i0 + il;
    float lgv = 0.f;
    if (PASS == 2 && t < 128)                   // prefetch: hides under dist
      lgv = logits[((size_t)(bq * 2 + (t >> 6)) * I_ + i) * O_ + (t & 63)];

    const uint4* __restrict__ vo =
        votes4 + (size_t)i * 4096 + (size_t)(bq * 2) * 256 + t;
    float2 f0[4], f1[4];
    unp8(vo[0],   f0);
    unp8(vo[256], f1);

    // distances: full 8-j dot in-thread, then 2-step xor over the 4-group
    float c0 = f0[0].x*av00.x + f0[0].y*av00.y + f0[1].x*av00.z + f0[1].y*av00.w
             + f0[2].x*av01.x + f0[2].y*av01.y + f0[3].x*av01.z + f0[3].y*av01.w;
    c0 += __shfl_xor(c0, 1);  c0 += __shfl_xor(c0, 2);
    float c1 = f1[0].x*av10.x + f1[0].y*av10.y + f1[1].x*av10.z + f1[1].y*av10.w
             + f1[2].x*av11.x + f1[2].y*av11.y + f1[3].x*av11.z + f1[3].y*av11.w;
    c1 += __shfl_xor(c1, 1);  c1 += __shfl_xor(c1, 2);
    if (l4 == 0) d_lds[o]      = c0;
    if (l4 == 1) d_lds[64 + o] = c1;
    __syncthreads();

    // softmax over o: waves 0-1, one (bb) each; lane = o
    float ellsave = 0.f;
    if (t < 128) {
      float ell = d_lds[t];
      if (PASS == 2) ell += lgv;
      ellsave = ell;
      float m = ell;
      m = fmaxf(m, __shfl_xor(m, 32)); m = fmaxf(m, __shfl_xor(m, 16));
      m = fmaxf(m, __shfl_xor(m, 8));  m = fmaxf(m, __shfl_xor(m, 4));
      m = fmaxf(m, __shfl_xor(m, 2));  m = fmaxf(m, __shfl_xor(m, 1));
      float e = __expf(ell - m);
      float sd = e;
      sd += __shfl_xor(sd, 32); sd += __shfl_xor(sd, 16); sd += __shfl_xor(sd, 8);
      sd += __shfl_xor(sd, 4);  sd += __shfl_xor(sd, 2);  sd += __shfl_xor(sd, 1);
      r_lds[t] = e / sd;
    }
    __syncthreads();

    if (PASS == 1 && t < 128)                   // deferred: drains next il
      logits[((size_t)(bq * 2 + (t >> 6)) * I_ + i) * O_ + (t & 63)] = ellsave;

    float r0 = r_lds[o], r1 = r_lds[64 + o];
    ac00.x = fmaf(r0, f0[0].x, ac00.x); ac00.y = fmaf(r0, f0[0].y, ac00.y);
    ac00.z = fmaf(r0, f0[1].x, ac00.z); ac00.w = fmaf(r0, f0[1].y, ac00.w);
    ac01.x = fmaf(r0, f0[2].x, ac01.x); ac01.y = fmaf(r0, f0[2].y, ac01.y);
    ac01.z = fmaf(r0, f0[3].x, ac01.z); ac01.w = fmaf(r0, f0[3].y, ac01.w);
    ac10.x = fmaf(r1, f1[0].x, ac10.x); ac10.y = fmaf(r1, f1[0].y, ac10.y);
    ac10.z = fmaf(r1, f1[1].x, ac10.z); ac10.w = fmaf(r1, f1[1].y, ac10.w);
    ac11.x = fmaf(r1, f1[2].x, ac11.x); ac11.y = fmaf(r1, f1[2].y, ac11.y);
    ac11.z = fmaf(r1, f1[3].x, ac11.z); ac11.w = fmaf(r1, f1[3].y, ac11.w);
  }

  // part f16 layout: [islab][16 b][1024 half2]
  uint4* __restrict__ po =
      part + (size_t)islab * 4096 + (size_t)(bq * 2) * 256 + t;
  po[0]   = pk8(ac00, ac01);
  po[256] = pk8(ac10, ac11);
}

// -------------------------------------------------------------------------
// reduce_squash_f16 — round-12 version.
// -------------------------------------------------------------------------
__global__ __launch_bounds__(256) void reduce_squash_f16(
    const uint4* __restrict__ part, const float* __restrict__ bias,
    float* __restrict__ out)
{
  __shared__ float red[64][4][8];              // 8 KB
  const int b = blockIdx.x >> 6, o = blockIdx.x & 63;
  const int t = threadIdx.x, s = t >> 2, q = t & 3;
  const uint4* __restrict__ base =
      part + (size_t)b * 256 + o * 4 + q;

  float r[8];
  #pragma unroll
  for (int e = 0; e < 8; ++e) r[e] = 0.f;
  #pragma unroll
  for (int k = 0; k < 4; ++k) {
    uint4 u = base[(size_t)(s + 64 * k) * 4096];   // islab stride
    float2 f[4];
    unp8(u, f);
    r[0] += f[0].x; r[1] += f[0].y; r[2] += f[1].x; r[3] += f[1].y;
    r[4] += f[2].x; r[5] += f[2].y; r[6] += f[3].x; r[7] += f[3].y;
  }
  #pragma unroll
  for (int e = 0; e < 8; ++e) red[s][q][e] = r[e];
  __syncthreads();

  if (t < 32) {
    const int q2 = t >> 3, e = t & 7;
    float p = 0.f;
    for (int s2 = 0; s2 < 64; ++s2) p += red[s2][q2][e];
    p += bias[o * 32 + q2 * 8 + e];
    float ns = p * p;
    ns += __shfl_xor(ns, 1);  ns += __shfl_xor(ns, 2);
    ns += __shfl_xor(ns, 4);  ns += __shfl_xor(ns, 8);
    ns += __shfl_xor(ns, 16);
    out[(size_t)b * J_ + o * 32 + q2 * 8 + e] = p * sqrtf(ns) / (1.0f + ns);
  }
}

// -------------------------------------------------------------------------
// FALLBACK (ws too small): W-streaming pass kernel with f32 part at
// islab*32768 + b*2048 + j, plus its f32 reducer.
// -------------------------------------------------------------------------
__global__ __launch_bounds__(256) void reduce_squash_f32(
    const float* __restrict__ part, const float* __restrict__ bias,
    float* __restrict__ out)
{
  __shared__ float4 red[32][8];
  const int b = blockIdx.x >> 6, o = blockIdx.x & 63;
  const int t = threadIdx.x, s = t >> 3, q = t & 7;
  const float4* __restrict__ base =
      (const float4*)part + (size_t)b * 512 + o * 8 + q;

  float4 acc = make_float4(0.f, 0.f, 0.f, 0.f);
  #pragma unroll
  for (int k = 0; k < 8; ++k) {
    float4 v = base[(size_t)(s + 32 * k) * 8192];
    acc.x += v.x; acc.y += v.y; acc.z += v.z; acc.w += v.w;
  }
  red[s][q] = acc;
  __syncthreads();

  if (t < 8) {
    float4 p = make_float4(0.f, 0.f, 0.f, 0.f);
    for (int s2 = 0; s2 < 32; ++s2) {
      float4 v = red[s2][t];
      p.x += v.x; p.y += v.y; p.z += v.z; p.w += v.w;
    }
    float4 bq4 = ((const float4*)bias)[o * 8 + t];
    p.x += bq4.x; p.y += bq4.y; p.z += bq4.z; p.w += bq4.w;
    float ns = p.x*p.x + p.y*p.y + p.z*p.z + p.w*p.w;
    ns += __shfl_xor(ns, 1);  ns += __shfl_xor(ns, 2);  ns += __shfl_xor(ns, 4);
    float sc = sqrtf(ns) / (1.0f + ns);
    ((float4*)out)[(size_t)b * 512 + o * 8 + t] =
        make_float4(p.x*sc, p.y*sc, p.z*sc, p.w*sc);
  }
}

template<int PASS>
__global__ __launch_bounds__(1024) void fb_pass_kernel(
    const float* __restrict__ x, const float* __restrict__ W,
    const float* __restrict__ act_in, float* __restrict__ part,
    float* __restrict__ logits)
{
  __shared__ float x_lds[8 * B_ * AIN_];
  __shared__ float d_lds[8 * O_];
  __shared__ float r_lds[8 * O_];
  const int tid = threadIdx.x, blk = blockIdx.x, i0 = blk * 8;
  for (int e = tid; e < 8 * B_ * AIN_; e += 1024) {
    int b = e >> 7, il = (e >> 4) & 7, a = e & 15;
    x_lds[il * 256 + b * 16 + a] =
        x[(size_t)b * (I_ * AIN_) + (size_t)(i0 + il) * AIN_ + a];
  }
  __syncthreads();
  const int og = tid >> 4, lg = tid & 15;
  float2 acc[16];
  #pragma unroll
  for (int b = 0; b < 16; ++b) acc[b] = make_float2(0.f, 0.f);
  const float2* __restrict__ Wq   = (const float2*)W;
  const float2* __restrict__ actq = (const float2*)act_in;
  for (int il = 0; il < 8; ++il) {
    const int i = i0 + il;
    const float2* __restrict__ Wi = Wq + (size_t)i * (AIN_ * JP_);
    const float4* __restrict__ xq = (const float4*)x_lds + il * 64;
    for (int h = 0; h < 2; ++h) {
      float2 v[8];
      #pragma unroll
      for (int bb = 0; bb < 8; ++bb) v[bb] = make_float2(0.f, 0.f);
      #pragma unroll
      for (int a4 = 0; a4 < 4; ++a4) {
        float2 w0 = Wi[(size_t)(a4 * 4 + 0) * JP_ + tid];
        float2 w1 = Wi[(size_t)(a4 * 4 + 1) * JP_ + tid];
        float2 w2 = Wi[(size_t)(a4 * 4 + 2) * JP_ + tid];
        float2 w3 = Wi[(size_t)(a4 * 4 + 3) * JP_ + tid];
        #pragma unroll
        for (int bb = 0; bb < 8; ++bb) {
          float4 xv = xq[(h * 8 + bb) * 4 + a4];
          v[bb].x = fmaf(xv.x, w0.x, v[bb].x); v[bb].y = fmaf(xv.x, w0.y, v[bb].y);
          v[bb].x = fmaf(xv.y, w1.x, v[bb].x); v[bb].y = fmaf(xv.y, w1.y, v[bb].y);
          v[bb].x = fmaf(xv.z, w2.x, v[bb].x); v[bb].y = fmaf(xv.z, w2.y, v[bb].y);
          v[bb].x = fmaf(xv.w, w3.x, v[bb].x); v[bb].y = fmaf(xv.w, w3.y, v[bb].y);
        }
      }
      if (PASS == 0) {
        #pragma unroll
        for (int bb = 0; bb < 8; ++bb) {
          acc[h * 8 + bb].x += v[bb].x; acc[h * 8 + bb].y += v[bb].y;
        }
      } else {
        #pragma unroll
        for (int bb = 0; bb < 8; ++bb) {
          const int b = h * 8 + bb;
          float2 avv = actq[(size_t)b * JP_ + tid];
          float c = v[bb].x * avv.x + v[bb].y * avv.y;
          c += __shfl_xor(c, 1); c += __shfl_xor(c, 2);
          c += __shfl_xor(c, 4); c += __shfl_xor(c, 8);
          if (lg == bb) d_lds[bb * 64 + og] = c;
        }
        __syncthreads();
        if (tid < 512) {
          const int bb2 = tid >> 6, o2 = tid & 63;
          const int b2  = h * 8 + bb2;
          float ell = d_lds[tid];
          if (PASS == 2) ell += logits[((size_t)b2 * I_ + i) * O_ + o2];
          if (PASS == 1) logits[((size_t)b2 * I_ + i) * O_ + o2] = ell;
          float m = ell;
          m = fmaxf(m, __shfl_xor(m, 32)); m = fmaxf(m, __shfl_xor(m, 16));
          m = fmaxf(m, __shfl_xor(m, 8));  m = fmaxf(m, __shfl_xor(m, 4));
          m = fmaxf(m, __shfl_xor(m, 2));  m = fmaxf(m, __shfl_xor(m, 1));
          float e = __expf(ell - m);
          float s = e;
          s += __shfl_xor(s, 32); s += __shfl_xor(s, 16); s += __shfl_xor(s, 8);
          s += __shfl_xor(s, 4);  s += __shfl_xor(s, 2);  s += __shfl_xor(s, 1);
          r_lds[tid] = e / s;
        }
        __syncthreads();
        #pragma unroll
        for (int bb = 0; bb < 8; ++bb) {
          float r = r_lds[bb * 64 + og];
          acc[h * 8 + bb].x = fmaf(r, v[bb].x, acc[h * 8 + bb].x);
          acc[h * 8 + bb].y = fmaf(r, v[bb].y, acc[h * 8 + bb].y);
        }
      }
    }
  }
  const float sc = (PASS == 0) ? (1.0f / 64.0f) : 1.0f;
  #pragma unroll
  for (int b = 0; b < 16; ++b) {
    float2* __restrict__ po = (float2*)part +
        (size_t)blk * (B_ * JP_) + (size_t)b * JP_ + tid;
    *po = make_float2(acc[b].x * sc, acc[b].y * sc);
  }
}

// -------------------------------------------------------------------------
extern "C" void kernel_launch(void* const* d_in, const int* in_sizes, int n_in,
                              void* d_out, int out_size, void* d_ws, size_t ws_size,
                              hipStream_t stream) {
  const float* x    = (const float*)d_in[0];
  const float* W    = (const float*)d_in[1];
  const float* bias = (const float*)d_in[2];
  float* out = (float*)d_out;

  float*   part   = (float*)d_ws;                        // 32 MiB region
  float*   act    = part + (size_t)256 * (B_ * J_);      // 128 KB
  float*   logits = act + (B_ * J_);                     // 8 MB
  __half2* votes  = (__half2*)(logits + (size_t)B_ * I_ * O_);  // 64 MB f16
  const size_t need = ((size_t)256 * B_ * J_ + B_ * J_ + (size_t)B_ * I_ * O_) * 4
                    + (size_t)I_ * B_ * JP_ * 4;

  if (ws_size >= need) {
    votes_p0_kernel<<<2048, 256, 0, stream>>>(x, W, votes, (__half2*)part);
    reduce_squash0_f16<<<1024, 256, 0, stream>>>((const uint4*)part, bias, act);
    route_kernel<1><<<2048, 256, 0, stream>>>((const uint4*)votes, act,
                                              (uint4*)part, logits);
    reduce_squash_f16<<<1024, 256, 0, stream>>>((const uint4*)part, bias, act);
    route_kernel<2><<<2048, 256, 0, stream>>>((const uint4*)votes, act,
                                              (uint4*)part, logits);
    reduce_squash_f16<<<1024, 256, 0, stream>>>((const uint4*)part, bias, out);
  } else {
    fb_pass_kernel<0><<<256, 1024, 0, stream>>>(x, W, act, part, logits);
    reduce_squash_f32<<<1024, 256, 0, stream>>>(part, bias, act);
    fb_pass_kernel<1><<<256, 1024, 0, stream>>>(x, W, act, part, logits);
    reduce_squash_f32<<<1024, 256, 0, stream>>>(part, bias, act);
    fb_pass_kernel<2><<<256, 1024, 0, stream>>>(x, W, act, part, logits);
    reduce_squash_f32<<<1024, 256, 0, stream>>>(part, bias, out);
  }
}